// Round 3
// baseline (1637.063 us; speedup 1.0000x reference)
//
#include <hip/hip_runtime.h>
#include <stdint.h>

#define BATCH 2048
#define DDIM 768
#define DICT 16384
#define NTOT (BATCH*DICT)
#define TOPK_TOTAL 65536
#define NDEAD_THR 15360
#define EPS 1e-5f
#define L1_COEFF 3.0e-4f
#define AUX_PENALTY 0.03125f
#define MU 1e-3f
#define CAND_CAP 2048
#define PROMO_CAP 64

// ---- d_out layout (floats) ----
#define OFF_YPRED 0
#define OFF_ACTS  (BATCH*DDIM)                  // 1572864
#define OFF_SCAL  (OFF_ACTS + (size_t)NTOT)     // 35127296
#define OFF_NBA   (OFF_SCAL + 7)

// ---- ws layout (32-bit units) ----
#define WS_HISTA 0
#define WS_HISTB 4096
#define WS_HISTC 8192          // 256 used
#define WS_CTRL  8448          // 16
#define WS_SCAL  8464          // 16
#define WS_COLCNT 8480         // 16384
#define WS_ZERO_END 24864
#define WS_CANDS 24864         // 2048
#define WS_PROMO 26912         // 3*64 = 192
#define WS_XENC  27104
#define WS_YPROC (WS_XENC + BATCH*DDIM)
#define WS_YMEAN (WS_YPROC + BATCH*DDIM)
#define WS_YSTD  (WS_YMEAN + BATCH)
#define WS_AUX   (WS_YSTD + BATCH)

struct Ctrl {
  unsigned b0, rank1, b1, rank2, t_bits, count_ge;
  unsigned cand_cnt, above_cnt, promo_cnt, pad0, pad1, pad2, pad3, pad4, pad5, pad6;
};
struct Scal {
  float l1_sum, l2_sum, aux_sum;
  unsigned l0_cnt, num_dead, dead_cnt, pad0, pad1;
};

__device__ __forceinline__ float blk_sum(float v, float* sh) {
#pragma unroll
  for (int o = 32; o; o >>= 1) v += __shfl_down(v, o, 64);
  int lane = threadIdx.x & 63, w = threadIdx.x >> 6;
  __syncthreads();
  if (lane == 0) sh[w] = v;
  __syncthreads();
  return sh[0] + sh[1] + sh[2] + sh[3];
}

// -------------------- init --------------------
__global__ void k_init(unsigned* ws) {
  int i = blockIdx.x * blockDim.x + threadIdx.x;
  if (i < WS_ZERO_END) ws[i] = 0u;
}

// -------------------- normalize x,y (fp32) --------------------
__global__ __launch_bounds__(256) void k_norm(
    const float* __restrict__ x_in, const float* __restrict__ y_t,
    const float* __restrict__ b_dec,
    float* __restrict__ x_enc, float* __restrict__ y_proc,
    float* __restrict__ y_mean, float* __restrict__ y_std) {
  int r = blockIdx.x, t = threadIdx.x;
  __shared__ float red[4];
  const float* xr = x_in + (size_t)r * DDIM;
  float v0 = xr[t], v1 = xr[t + 256], v2 = xr[t + 512];
  float s = blk_sum(v0 + v1 + v2, red);
  float mean = s * (1.0f / DDIM);
  float d0 = v0 - mean, d1 = v1 - mean, d2 = v2 - mean;
  float ss = blk_sum(d0*d0 + d1*d1 + d2*d2, red);
  float stdv = sqrtf(ss * (1.0f / (DDIM - 1)));
  float inv = 1.0f / (stdv + EPS);
  float* xe = x_enc + (size_t)r * DDIM;
  xe[t]       = d0 * inv - b_dec[t];
  xe[t + 256] = d1 * inv - b_dec[t + 256];
  xe[t + 512] = d2 * inv - b_dec[t + 512];
  const float* yr = y_t + (size_t)r * DDIM;
  v0 = yr[t]; v1 = yr[t + 256]; v2 = yr[t + 512];
  s = blk_sum(v0 + v1 + v2, red);
  mean = s * (1.0f / DDIM);
  d0 = v0 - mean; d1 = v1 - mean; d2 = v2 - mean;
  ss = blk_sum(d0*d0 + d1*d1 + d2*d2, red);
  stdv = sqrtf(ss * (1.0f / (DDIM - 1)));
  inv = 1.0f / (stdv + EPS);
  float* yp = y_proc + (size_t)r * DDIM;
  yp[t]       = d0 * inv;
  yp[t + 256] = d1 * inv;
  yp[t + 512] = d2 * inv;
  if (t == 0) { y_mean[r] = mean; y_std[r] = stdv; }
}

// -------------------- fp32 encoder GEMM --------------------
#define BM 128
#define BN 128
#define BK 8
__global__ __launch_bounds__(256) void k_gemm(
    const float* __restrict__ A, const float* __restrict__ B,
    const float* __restrict__ b_enc, float* __restrict__ C) {
  __shared__ float As[BK][BM];
  __shared__ float Bs[BK][BN];
  int m0 = blockIdx.y * BM, n0 = blockIdx.x * BN;
  int t = threadIdx.x;
  float acc[8][8] = {};
  int am = t >> 1, aq = (t & 1) * 4;
  int bk = t >> 5, bc = (t & 31) * 4;
  const float* Aptr = A + (size_t)(m0 + am) * DDIM + aq;
  const float* Bptr = B + (size_t)bk * DICT + n0 + bc;
  int tm = (t >> 4) * 8, tn = (t & 15) * 8;
  for (int k0 = 0; k0 < DDIM; k0 += BK) {
    float4 av = *(const float4*)(Aptr + k0);
    float4 bv = *(const float4*)(Bptr + (size_t)k0 * DICT);
    As[aq + 0][am] = av.x; As[aq + 1][am] = av.y;
    As[aq + 2][am] = av.z; As[aq + 3][am] = av.w;
    *(float4*)&Bs[bk][bc] = bv;
    __syncthreads();
#pragma unroll
    for (int k = 0; k < BK; ++k) {
      float a[8], b[8];
      *(float4*)(a)     = *(float4*)&As[k][tm];
      *(float4*)(a + 4) = *(float4*)&As[k][tm + 4];
      *(float4*)(b)     = *(float4*)&Bs[k][tn];
      *(float4*)(b + 4) = *(float4*)&Bs[k][tn + 4];
#pragma unroll
      for (int i = 0; i < 8; ++i)
#pragma unroll
        for (int j = 0; j < 8; ++j)
          acc[i][j] = fmaf(a[i], b[j], acc[i][j]);
    }
    __syncthreads();
  }
  float be[8];
  *(float4*)(be)     = *(const float4*)&b_enc[n0 + tn];
  *(float4*)(be + 4) = *(const float4*)&b_enc[n0 + tn + 4];
#pragma unroll
  for (int i = 0; i < 8; ++i) {
    size_t row = (size_t)(m0 + tm + i);
    float o[8];
#pragma unroll
    for (int j = 0; j < 8; ++j) {
      float v = acc[i][j] + be[j];
      o[j] = v > 0.0f ? v : 0.0f;
    }
    *(float4*)&C[row * DICT + n0 + tn]     = *(float4*)(o);
    *(float4*)&C[row * DICT + n0 + tn + 4] = *(float4*)(o + 4);
  }
}

// -------------------- radix-select histograms (3 passes) --------------------
__global__ void k_histA(const float4* __restrict__ acts, unsigned* __restrict__ hist) {
  __shared__ unsigned h[4096];
  for (int i = threadIdx.x; i < 4096; i += 256) h[i] = 0;
  __syncthreads();
  unsigned zc = 0;
  int n4 = NTOT / 4;
  for (int i = blockIdx.x * blockDim.x + threadIdx.x; i < n4; i += gridDim.x * blockDim.x) {
    float4 v = acts[i];
    unsigned u;
    u = __float_as_uint(v.x); if (u) atomicAdd(&h[u >> 20], 1u); else zc++;
    u = __float_as_uint(v.y); if (u) atomicAdd(&h[u >> 20], 1u); else zc++;
    u = __float_as_uint(v.z); if (u) atomicAdd(&h[u >> 20], 1u); else zc++;
    u = __float_as_uint(v.w); if (u) atomicAdd(&h[u >> 20], 1u); else zc++;
  }
  if (zc) atomicAdd(&h[0], zc);
  __syncthreads();
  for (int i = threadIdx.x; i < 4096; i += 256) if (h[i]) atomicAdd(&hist[i], h[i]);
}

__global__ void k_histB(const float4* __restrict__ acts, const Ctrl* __restrict__ c,
                        unsigned* __restrict__ hist) {
  __shared__ unsigned h[4096];
  for (int i = threadIdx.x; i < 4096; i += 256) h[i] = 0;
  __syncthreads();
  unsigned b0 = c->b0;
  int n4 = NTOT / 4;
  for (int i = blockIdx.x * blockDim.x + threadIdx.x; i < n4; i += gridDim.x * blockDim.x) {
    float4 v = acts[i];
    unsigned u;
    u = __float_as_uint(v.x); if ((u >> 20) == b0) atomicAdd(&h[(u >> 8) & 0xFFF], 1u);
    u = __float_as_uint(v.y); if ((u >> 20) == b0) atomicAdd(&h[(u >> 8) & 0xFFF], 1u);
    u = __float_as_uint(v.z); if ((u >> 20) == b0) atomicAdd(&h[(u >> 8) & 0xFFF], 1u);
    u = __float_as_uint(v.w); if ((u >> 20) == b0) atomicAdd(&h[(u >> 8) & 0xFFF], 1u);
  }
  __syncthreads();
  for (int i = threadIdx.x; i < 4096; i += 256) if (h[i]) atomicAdd(&hist[i], h[i]);
}

__global__ void k_histC(const float4* __restrict__ acts, const Ctrl* __restrict__ c,
                        unsigned* __restrict__ hist) {
  __shared__ unsigned h[256];
  if (threadIdx.x < 256) h[threadIdx.x] = 0;
  __syncthreads();
  unsigned pfx = (c->b0 << 12) | c->b1;
  int n4 = NTOT / 4;
  for (int i = blockIdx.x * blockDim.x + threadIdx.x; i < n4; i += gridDim.x * blockDim.x) {
    float4 v = acts[i];
    unsigned u;
    u = __float_as_uint(v.x); if ((u >> 8) == pfx) atomicAdd(&h[u & 0xFF], 1u);
    u = __float_as_uint(v.y); if ((u >> 8) == pfx) atomicAdd(&h[u & 0xFF], 1u);
    u = __float_as_uint(v.z); if ((u >> 8) == pfx) atomicAdd(&h[u & 0xFF], 1u);
    u = __float_as_uint(v.w); if ((u >> 8) == pfx) atomicAdd(&h[u & 0xFF], 1u);
  }
  __syncthreads();
  if (threadIdx.x < 256 && h[threadIdx.x]) atomicAdd(&hist[threadIdx.x], h[threadIdx.x]);
}

// -------------------- parallel rank-select --------------------
template<int NB>
__global__ __launch_bounds__(256) void k_sel(const unsigned* __restrict__ hist,
                                             Ctrl* c, int pass) {
  __shared__ unsigned sts[256];
  int t = threadIdx.x;
  unsigned K = (pass == 0) ? TOPK_TOTAL : (pass == 1 ? c->rank1 : c->rank2);
  constexpr int PER = NB / 256;
  unsigned h[PER];
  unsigned ts = 0;
#pragma unroll
  for (int i = 0; i < PER; ++i) { h[i] = hist[t * PER + i]; ts += h[i]; }
  sts[t] = ts;
  __syncthreads();
  unsigned suf = 0;
  for (int j = t + 1; j < 256; ++j) suf += sts[j];
  if (suf < K && K <= suf + ts) {
    unsigned cum = suf;
    for (int i = PER - 1; i >= 0; --i) {
      unsigned n = h[i];
      if (cum + n >= K) {
        unsigned b = (unsigned)(t * PER + i);
        if (pass == 0)      { c->b0 = b; c->rank1 = K - cum; }
        else if (pass == 1) { c->b1 = b; c->rank2 = K - cum; }
        else {
          c->t_bits = (c->b0 << 20) | (c->b1 << 8) | b;
          c->count_ge = cum + n;
        }
        break;
      }
      cum += n;
    }
  }
}

// -------------------- fused: column counts + boundary candidates --------------------
__global__ void k_fused(const float4* __restrict__ acts, Ctrl* c,
                        unsigned* __restrict__ col_cnt, unsigned* __restrict__ cands) {
  unsigned tb = c->t_bits;
  float t = __uint_as_float(tb);
  float lo = t - MU, hi = t + MU;
  unsigned above = 0;
  int n4 = NTOT / 4;
  for (int i = blockIdx.x * blockDim.x + threadIdx.x; i < n4; i += gridDim.x * blockDim.x) {
    float4 fv = acts[i];
    int base = i * 4;
#pragma unroll
    for (int q = 0; q < 4; ++q) {
      float v = (q == 0) ? fv.x : (q == 1) ? fv.y : (q == 2) ? fv.z : fv.w;
      if (__float_as_uint(v) >= tb) atomicAdd(&col_cnt[(base + q) & (DICT - 1)], 1u);
      if (v > hi) above++;
      else if (v >= lo) {
        unsigned p = atomicAdd(&c->cand_cnt, 1u);
        if (p < CAND_CAP) cands[p] = (unsigned)(base + q);
      }
    }
  }
  if (above) atomicAdd(&c->above_cnt, above);
}

// -------------------- fp64 boundary refinement (1 block) --------------------
__global__ __launch_bounds__(256) void k_refine(
    const float* __restrict__ x_in, const float* __restrict__ W_enc,
    const float* __restrict__ b_enc, const float* __restrict__ b_dec,
    float* __restrict__ acts, Ctrl* c,
    unsigned* __restrict__ col_cnt, const unsigned* __restrict__ cands,
    unsigned* __restrict__ promo) {
  __shared__ double v64[CAND_CAP];
  int t = threadIdx.x;
  unsigned cc = c->cand_cnt;
  if (cc > CAND_CAP) return;   // fallback: keep fp32 decisions
  int n = (int)cc;
  unsigned tb = c->t_bits;
  int Kp = (int)(TOPK_TOTAL - c->above_cnt);   // how many to select among candidates
  for (int i = t; i < n; i += 256) {
    unsigned idx = cands[i];
    int r = (int)(idx >> 14), j = (int)(idx & (DICT - 1));
    const float* xr = x_in + (size_t)r * DDIM;
    double m = 0.0;
    for (int q = 0; q < DDIM; ++q) m += (double)xr[q];
    m *= (1.0 / DDIM);
    double ss = 0.0;
    for (int q = 0; q < DDIM; ++q) { double d = (double)xr[q] - m; ss += d * d; }
    double stdv = sqrt(ss * (1.0 / (DDIM - 1)));
    double inv = 1.0 / (stdv + 1e-5);
    double acc = (double)b_enc[j];
    for (int q = 0; q < DDIM; ++q) {
      double xe = ((double)xr[q] - m) * inv - (double)b_dec[q];
      acc += xe * (double)W_enc[(size_t)q * DICT + j];
    }
    v64[i] = acc;
  }
  __syncthreads();
  for (int i = t; i < n; i += 256) {
    unsigned idx = cands[i];
    double my = v64[i];
    int rank = 0;
    for (int s = 0; s < n; ++s)
      rank += (v64[s] > my || (v64[s] == my && cands[s] < idx)) ? 1 : 0;
    bool sel64 = (rank < Kp);
    int j = (int)(idx & (DICT - 1));
    float v32 = acts[idx];
    bool sel32 = (__float_as_uint(v32) >= tb);
    if (sel32 && !sel64) {           // demote
      acts[idx] = 0.0f;
      atomicSub(&col_cnt[j], 1u);
    } else if (!sel32 && sel64) {    // promote
      unsigned p = atomicAdd(&c->promo_cnt, 1u);
      if (p < PROMO_CAP) {
        promo[p * 3 + 0] = idx >> 14;
        promo[p * 3 + 1] = (unsigned)j;
        promo[p * 3 + 2] = __float_as_uint(v32);
      }
      atomicAdd(&col_cnt[j], 1u);
    }
  }
}

// -------------------- dead bookkeeping --------------------
__global__ void k_dead(const int* __restrict__ nba_in, const unsigned* __restrict__ col_cnt,
                       Scal* sc, unsigned* __restrict__ deadlist, float* __restrict__ nba_out) {
  int j = blockIdx.x * blockDim.x + threadIdx.x;
  if (j >= DICT) return;
  int nn = (col_cnt[j] > 0) ? 0 : (nba_in[j] + 1);
  nba_out[j] = (float)nn;
  if (nn >= NDEAD_THR) { unsigned p = atomicAdd(&sc->dead_cnt, 1u); deadlist[p] = (unsigned)j; }
  if (nn > NDEAD_THR) atomicAdd(&sc->num_dead, 1u);
}

// -------------------- aux decode (dead columns only) --------------------
__global__ __launch_bounds__(256) void k_aux(
    const float* __restrict__ acts_dense, const float* __restrict__ W_dec,
    const Scal* __restrict__ sc, const unsigned* __restrict__ deadlist,
    float* __restrict__ y_pred_aux) {
  int r = blockIdx.y;
  int cidx = blockIdx.x * 256 + threadIdx.x;
  __shared__ float sv[256];
  __shared__ unsigned sj[256];
  int Dn = (int)sc->dead_cnt;
  float s = 0.0f;
  for (int base = 0; base < Dn; base += 256) {
    int n = min(256, Dn - base);
    __syncthreads();
    if (threadIdx.x < n) {
      unsigned j = deadlist[base + threadIdx.x];
      sj[threadIdx.x] = j;
      sv[threadIdx.x] = acts_dense[(size_t)r * DICT + j];
    }
    __syncthreads();
    for (int i = 0; i < n; ++i)
      s = fmaf(sv[i], W_dec[(size_t)sj[i] * DDIM + cidx], s);
  }
  y_pred_aux[(size_t)r * DDIM + cidx] = s;
}

// -------------------- per-row: sparsify + decode + losses --------------------
__global__ __launch_bounds__(256) void k_row(
    float* __restrict__ acts, const float* __restrict__ W_dec,
    const float* __restrict__ b_dec, const float* __restrict__ y_proc,
    const float* __restrict__ y_mean, const float* __restrict__ y_std,
    const float* __restrict__ y_pred_aux, const Ctrl* __restrict__ ctrl,
    const unsigned* __restrict__ promo,
    Scal* sc, float* __restrict__ y_pred_out) {
  int r = blockIdx.x, t = threadIdx.x;
  __shared__ int s_idx[2048];
  __shared__ float s_val[2048];
  __shared__ int s_cnt;
  __shared__ float red[4];
  if (t == 0) s_cnt = 0;
  __syncthreads();
  unsigned tb = ctrl->t_bits;
  float l1p = 0.0f;
  float* arow = acts + (size_t)r * DICT;
  for (int i = t; i < DICT; i += 256) {
    float v = arow[i];
    if (__float_as_uint(v) >= tb) {
      int p = atomicAdd(&s_cnt, 1);
      if (p < 2048) { s_idx[p] = i; s_val[p] = v; }
      l1p += v;
    } else {
      arow[i] = 0.0f;
    }
  }
  __syncthreads();
  // promoted elements (fp64-selected but below fp32 threshold)
  if (t == 0) {
    int pc = (int)min(ctrl->promo_cnt, (unsigned)PROMO_CAP);
    for (int p = 0; p < pc; ++p) {
      if ((int)promo[p * 3 + 0] == r) {
        int cpos = (int)promo[p * 3 + 1];
        float v = __uint_as_float(promo[p * 3 + 2]);
        int q = s_cnt;
        if (q < 2048) { s_idx[q] = cpos; s_val[q] = v; s_cnt = q + 1; }
        arow[cpos] = v;   // restore into acts output (main scan zeroed it)
        l1p += v;
      }
    }
  }
  __syncthreads();
  int m = min(s_cnt, 2048);
  float l1tot = blk_sum(l1p, red);
  if (t == 0) {
    atomicAdd(&sc->l1_sum, l1tot);
    atomicAdd(&sc->l0_cnt, (unsigned)m);
  }
  float l2p = 0.0f, auxp = 0.0f;
  float ym = y_mean[r], ys = y_std[r];
  for (int cpos = t; cpos < DDIM; cpos += 256) {
    float accv = b_dec[cpos];
    for (int i = 0; i < m; ++i)
      accv = fmaf(s_val[i], W_dec[(size_t)s_idx[i] * DDIM + cpos], accv);
    float yp = y_proc[(size_t)r * DDIM + cpos];
    float d = accv - yp;
    l2p += d * d;
    float da = y_pred_aux[(size_t)r * DDIM + cpos] + d;
    auxp += da * da;
    y_pred_out[(size_t)r * DDIM + cpos] = accv * ys + ym;
  }
  float l2t = blk_sum(l2p, red);
  float auxt = blk_sum(auxp, red);
  if (t == 0) {
    atomicAdd(&sc->l2_sum, l2t);
    atomicAdd(&sc->aux_sum, auxt);
  }
}

// -------------------- finalize scalars --------------------
__global__ void k_fin(const Scal* __restrict__ sc, float* __restrict__ out_scal) {
  if (threadIdx.x == 0 && blockIdx.x == 0) {
    float inv_bd = 1.0f / (float)(BATCH * DDIM);
    float l2 = sc->l2_sum * inv_bd;
    float l0 = (float)sc->l0_cnt * (1.0f / BATCH);
    float l1 = sc->l1_sum * (1.0f / BATCH);
    float l1l = L1_COEFF * l1;
    float aux = sc->dead_cnt ? AUX_PENALTY * sc->aux_sum * inv_bd : 0.0f;
    out_scal[0] = l2 + l1l + aux;
    out_scal[1] = l2;
    out_scal[2] = l0;
    out_scal[3] = l1;
    out_scal[4] = l1l;
    out_scal[5] = aux;
    out_scal[6] = (float)sc->num_dead;
  }
}

extern "C" void kernel_launch(void* const* d_in, const int* in_sizes, int n_in,
                              void* d_out, int out_size, void* d_ws, size_t ws_size,
                              hipStream_t stream) {
  const float* x_in  = (const float*)d_in[0];
  const float* y_t   = (const float*)d_in[1];
  const float* W_enc = (const float*)d_in[2];
  const float* b_enc = (const float*)d_in[3];
  const float* W_dec = (const float*)d_in[4];
  const float* b_dec = (const float*)d_in[5];
  const int*   nba   = (const int*)d_in[6];

  float* out = (float*)d_out;
  float* acts = out + OFF_ACTS;
  float* ws = (float*)d_ws;
  unsigned* wsu = (unsigned*)d_ws;
  Ctrl* ctrl = (Ctrl*)(wsu + WS_CTRL);
  Scal* scal = (Scal*)(wsu + WS_SCAL);

  float* x_enc  = ws + WS_XENC;
  float* y_proc = ws + WS_YPROC;
  float* y_mean = ws + WS_YMEAN;
  float* y_std  = ws + WS_YSTD;
  float* y_aux  = ws + WS_AUX;

  k_init<<<(WS_ZERO_END + 255) / 256, 256, 0, stream>>>(wsu);
  k_norm<<<BATCH, 256, 0, stream>>>(x_in, y_t, b_dec, x_enc, y_proc, y_mean, y_std);
  k_gemm<<<dim3(DICT / BN, BATCH / BM), 256, 0, stream>>>(x_enc, W_enc, b_enc, acts);
  k_histA<<<2048, 256, 0, stream>>>((const float4*)acts, wsu + WS_HISTA);
  k_sel<4096><<<1, 256, 0, stream>>>(wsu + WS_HISTA, ctrl, 0);
  k_histB<<<2048, 256, 0, stream>>>((const float4*)acts, ctrl, wsu + WS_HISTB);
  k_sel<4096><<<1, 256, 0, stream>>>(wsu + WS_HISTB, ctrl, 1);
  k_histC<<<2048, 256, 0, stream>>>((const float4*)acts, ctrl, wsu + WS_HISTC);
  k_sel<256><<<1, 256, 0, stream>>>(wsu + WS_HISTC, ctrl, 2);
  k_fused<<<2048, 256, 0, stream>>>((const float4*)acts, ctrl, wsu + WS_COLCNT, wsu + WS_CANDS);
  k_refine<<<1, 256, 0, stream>>>(x_in, W_enc, b_enc, b_dec, acts, ctrl,
                                  wsu + WS_COLCNT, wsu + WS_CANDS, wsu + WS_PROMO);
  k_dead<<<DICT / 256, 256, 0, stream>>>(nba, wsu + WS_COLCNT, scal, wsu + WS_CANDS + 0,
                                         out + OFF_NBA);
  // NOTE: deadlist reuses WS_CANDS region (candidates no longer needed after k_refine)
  k_aux<<<dim3(DDIM / 256, BATCH), 256, 0, stream>>>(acts, W_dec, scal, wsu + WS_CANDS, y_aux);
  k_row<<<BATCH, 256, 0, stream>>>(acts, W_dec, b_dec, y_proc, y_mean, y_std, y_aux,
                                   ctrl, wsu + WS_PROMO, scal, out + OFF_YPRED);
  k_fin<<<1, 64, 0, stream>>>(scal, out + OFF_SCAL);
}

// Round 7
// 1186.452 us; speedup vs baseline: 1.3798x; 1.3798x over previous
//
#include <hip/hip_runtime.h>
#include <stdint.h>

#define BATCH 2048
#define DDIM 768
#define DICT 16384
#define NTOT (BATCH*DICT)
#define TOPK_TOTAL 65536
#define NDEAD_THR 15360
#define EPS 1e-5f
#define L1_COEFF 3.0e-4f
#define AUX_PENALTY 0.03125f
#define MU 1e-3f
#define CAND_CAP 2048
#define PROMO_CAP 64

// ---- d_out layout (floats) ----
#define OFF_YPRED 0
#define OFF_ACTS  (BATCH*DDIM)                  // 1572864
#define OFF_SCAL  (OFF_ACTS + (size_t)NTOT)     // 35127296
#define OFF_NBA   (OFF_SCAL + 7)

// ---- ws layout (32-bit units) ----
#define WS_HISTA 0
#define WS_HISTB 4096          // also reused as WS_V64 (2048 doubles) after selB
#define WS_HISTC 8192          // 256 used
#define WS_CTRL  8448          // 16
#define WS_SCAL  8464          // 16
#define WS_COLCNT 8480         // 16384
#define WS_ZERO_END 24864
#define WS_CANDS 24864         // 2048 (reused as deadlist after refine)
#define WS_PROMO 26912         // 3*64 = 192
#define WS_XENC  27104
#define WS_YPROC (WS_XENC + BATCH*DDIM)
#define WS_YMEAN (WS_YPROC + BATCH*DDIM)
#define WS_YSTD  (WS_YMEAN + BATCH)
#define WS_AUX   (WS_YSTD + BATCH)
#define WS_RMEAN (WS_AUX + BATCH*DDIM)      // 2048 doubles = 4096 u32 (even offset)
#define WS_RINV  (WS_RMEAN + 2*BATCH)       // 2048 doubles
#define WS_V64   WS_HISTB

struct Ctrl {
  unsigned b0, rank1, b1, rank2, t_bits, count_ge;
  unsigned cand_cnt, above_cnt, promo_cnt, pad0, pad1, pad2, pad3, pad4, pad5, pad6;
};
struct Scal {
  float l1_sum, l2_sum, aux_sum;
  unsigned l0_cnt, num_dead, dead_cnt, pad0, pad1;
};

__device__ __forceinline__ float blk_sum(float v, float* sh) {
#pragma unroll
  for (int o = 32; o; o >>= 1) v += __shfl_down(v, o, 64);
  int lane = threadIdx.x & 63, w = threadIdx.x >> 6;
  __syncthreads();
  if (lane == 0) sh[w] = v;
  __syncthreads();
  return sh[0] + sh[1] + sh[2] + sh[3];
}

__device__ __forceinline__ double blk_sum_d(double v, double* shd) {
#pragma unroll
  for (int o = 32; o; o >>= 1) v += __shfl_down(v, o, 64);
  int lane = threadIdx.x & 63, w = threadIdx.x >> 6;
  __syncthreads();
  if (lane == 0) shd[w] = v;
  __syncthreads();
  return shd[0] + shd[1] + shd[2] + shd[3];
}

// -------------------- init --------------------
__global__ void k_init(unsigned* ws) {
  int i = blockIdx.x * blockDim.x + threadIdx.x;
  if (i < WS_ZERO_END) ws[i] = 0u;
}

// -------------------- normalize x,y (fp32) + fp64 x row-stats --------------------
__global__ __launch_bounds__(256) void k_norm(
    const float* __restrict__ x_in, const float* __restrict__ y_t,
    const float* __restrict__ b_dec,
    float* __restrict__ x_enc, float* __restrict__ y_proc,
    float* __restrict__ y_mean, float* __restrict__ y_std,
    double* __restrict__ rmean_d, double* __restrict__ rinv_d) {
  int r = blockIdx.x, t = threadIdx.x;
  __shared__ float red[4];
  __shared__ double redd[4];
  // ---- x (fp32 path) ----
  const float* xr = x_in + (size_t)r * DDIM;
  float v0 = xr[t], v1 = xr[t + 256], v2 = xr[t + 512];
  float s = blk_sum(v0 + v1 + v2, red);
  float mean = s * (1.0f / DDIM);
  float d0 = v0 - mean, d1 = v1 - mean, d2 = v2 - mean;
  float ss = blk_sum(d0*d0 + d1*d1 + d2*d2, red);
  float stdv = sqrtf(ss * (1.0f / (DDIM - 1)));
  float inv = 1.0f / (stdv + EPS);
  float* xe = x_enc + (size_t)r * DDIM;
  xe[t]       = d0 * inv - b_dec[t];
  xe[t + 256] = d1 * inv - b_dec[t + 256];
  xe[t + 512] = d2 * inv - b_dec[t + 512];
  // ---- x fp64 stats for refine ----
  double sd = blk_sum_d((double)v0 + (double)v1 + (double)v2, redd);
  double md = sd * (1.0 / DDIM);
  double e0 = (double)v0 - md, e1 = (double)v1 - md, e2 = (double)v2 - md;
  double ssd = blk_sum_d(e0*e0 + e1*e1 + e2*e2, redd);
  double invd = 1.0 / (sqrt(ssd * (1.0 / (DDIM - 1))) + 1e-5);
  if (t == 0) { rmean_d[r] = md; rinv_d[r] = invd; }
  // ---- y ----
  const float* yr = y_t + (size_t)r * DDIM;
  v0 = yr[t]; v1 = yr[t + 256]; v2 = yr[t + 512];
  s = blk_sum(v0 + v1 + v2, red);
  mean = s * (1.0f / DDIM);
  d0 = v0 - mean; d1 = v1 - mean; d2 = v2 - mean;
  ss = blk_sum(d0*d0 + d1*d1 + d2*d2, red);
  stdv = sqrtf(ss * (1.0f / (DDIM - 1)));
  inv = 1.0f / (stdv + EPS);
  float* yp = y_proc + (size_t)r * DDIM;
  yp[t]       = d0 * inv;
  yp[t + 256] = d1 * inv;
  yp[t + 512] = d2 * inv;
  if (t == 0) { y_mean[r] = mean; y_std[r] = stdv; }
}

// -------------------- fp32 encoder GEMM --------------------
// C[2048 x 16384] = relu(A[2048x768] @ B[768x16384] + b_enc)
#define BM 128
#define BN 128
#define BK 16
#define BSTR (BK*8 + 4)   // 132: per-8-col-group stride (2-way banks on read = free)
__global__ __launch_bounds__(256) void k_gemm(
    const float* __restrict__ A, const float* __restrict__ B,
    const float* __restrict__ b_enc, float* __restrict__ C) {
  __shared__ float As[BK][BM];          // 8192 B
  __shared__ float Bs[16 * BSTR];       // 16 groups x 132 = 8448 B
  int m0 = blockIdx.y * BM, n0 = blockIdx.x * BN;
  int t = threadIdx.x;
  float acc[8][8] = {};
  int am = t >> 1, aq = (t & 1) * 8;
  int bk = t >> 5, bc = (t & 31) * 4;
  const float* Aptr = A + (size_t)(m0 + am) * DDIM + aq;
  const float* Bptr = B + (size_t)bk * DICT + n0 + bc;
  int tm = (t >> 4) * 8, tn8 = (t & 15);
  int bs_w0 = (bc >> 3) * BSTR + bk * 8 + (bc & 7);
  int bs_w1 = (bc >> 3) * BSTR + (bk + 8) * 8 + (bc & 7);
  for (int k0 = 0; k0 < DDIM; k0 += BK) {
    float4 a0 = *(const float4*)(Aptr + k0);
    float4 a1 = *(const float4*)(Aptr + k0 + 4);
    float4 b0 = *(const float4*)(Bptr + (size_t)k0 * DICT);
    float4 b1 = *(const float4*)(Bptr + (size_t)(k0 + 8) * DICT);
    As[aq + 0][am] = a0.x; As[aq + 1][am] = a0.y;
    As[aq + 2][am] = a0.z; As[aq + 3][am] = a0.w;
    As[aq + 4][am] = a1.x; As[aq + 5][am] = a1.y;
    As[aq + 6][am] = a1.z; As[aq + 7][am] = a1.w;
    *(float4*)&Bs[bs_w0] = b0;
    *(float4*)&Bs[bs_w1] = b1;
    __syncthreads();
#pragma unroll
    for (int k = 0; k < BK; ++k) {
      float a[8], b[8];
      *(float4*)(a)     = *(float4*)&As[k][tm];
      *(float4*)(a + 4) = *(float4*)&As[k][tm + 4];
      const float* bp = &Bs[tn8 * BSTR + k * 8];
      *(float4*)(b)     = *(const float4*)(bp);
      *(float4*)(b + 4) = *(const float4*)(bp + 4);
#pragma unroll
      for (int i = 0; i < 8; ++i)
#pragma unroll
        for (int j = 0; j < 8; ++j)
          acc[i][j] = fmaf(a[i], b[j], acc[i][j]);
    }
    __syncthreads();
  }
  int tn = tn8 * 8;
  float be[8];
  *(float4*)(be)     = *(const float4*)&b_enc[n0 + tn];
  *(float4*)(be + 4) = *(const float4*)&b_enc[n0 + tn + 4];
#pragma unroll
  for (int i = 0; i < 8; ++i) {
    size_t row = (size_t)(m0 + tm + i);
    float o[8];
#pragma unroll
    for (int j = 0; j < 8; ++j) {
      float v = acc[i][j] + be[j];
      o[j] = v > 0.0f ? v : 0.0f;
    }
    *(float4*)&C[row * DICT + n0 + tn]     = *(float4*)(o);
    *(float4*)&C[row * DICT + n0 + tn + 4] = *(float4*)(o + 4);
  }
}

// -------------------- radix-select histograms (3 passes) --------------------
__global__ void k_histA(const float4* __restrict__ acts, unsigned* __restrict__ hist) {
  __shared__ unsigned h[4096];
  for (int i = threadIdx.x; i < 4096; i += 256) h[i] = 0;
  __syncthreads();
  unsigned zc = 0;
  int n4 = NTOT / 4;
  for (int i = blockIdx.x * blockDim.x + threadIdx.x; i < n4; i += gridDim.x * blockDim.x) {
    float4 v = acts[i];
    unsigned u;
    u = __float_as_uint(v.x); if (u) atomicAdd(&h[u >> 20], 1u); else zc++;
    u = __float_as_uint(v.y); if (u) atomicAdd(&h[u >> 20], 1u); else zc++;
    u = __float_as_uint(v.z); if (u) atomicAdd(&h[u >> 20], 1u); else zc++;
    u = __float_as_uint(v.w); if (u) atomicAdd(&h[u >> 20], 1u); else zc++;
  }
  if (zc) atomicAdd(&h[0], zc);
  __syncthreads();
  for (int i = threadIdx.x; i < 4096; i += 256) if (h[i]) atomicAdd(&hist[i], h[i]);
}

__global__ void k_histB(const float4* __restrict__ acts, const Ctrl* __restrict__ c,
                        unsigned* __restrict__ hist) {
  __shared__ unsigned h[4096];
  for (int i = threadIdx.x; i < 4096; i += 256) h[i] = 0;
  __syncthreads();
  unsigned b0 = c->b0;
  int n4 = NTOT / 4;
  for (int i = blockIdx.x * blockDim.x + threadIdx.x; i < n4; i += gridDim.x * blockDim.x) {
    float4 v = acts[i];
    unsigned u;
    u = __float_as_uint(v.x); if ((u >> 20) == b0) atomicAdd(&h[(u >> 8) & 0xFFF], 1u);
    u = __float_as_uint(v.y); if ((u >> 20) == b0) atomicAdd(&h[(u >> 8) & 0xFFF], 1u);
    u = __float_as_uint(v.z); if ((u >> 20) == b0) atomicAdd(&h[(u >> 8) & 0xFFF], 1u);
    u = __float_as_uint(v.w); if ((u >> 20) == b0) atomicAdd(&h[(u >> 8) & 0xFFF], 1u);
  }
  __syncthreads();
  for (int i = threadIdx.x; i < 4096; i += 256) if (h[i]) atomicAdd(&hist[i], h[i]);
}

__global__ void k_histC(const float4* __restrict__ acts, const Ctrl* __restrict__ c,
                        unsigned* __restrict__ hist) {
  __shared__ unsigned h[256];
  if (threadIdx.x < 256) h[threadIdx.x] = 0;
  __syncthreads();
  unsigned pfx = (c->b0 << 12) | c->b1;
  int n4 = NTOT / 4;
  for (int i = blockIdx.x * blockDim.x + threadIdx.x; i < n4; i += gridDim.x * blockDim.x) {
    float4 v = acts[i];
    unsigned u;
    u = __float_as_uint(v.x); if ((u >> 8) == pfx) atomicAdd(&h[u & 0xFF], 1u);
    u = __float_as_uint(v.y); if ((u >> 8) == pfx) atomicAdd(&h[u & 0xFF], 1u);
    u = __float_as_uint(v.z); if ((u >> 8) == pfx) atomicAdd(&h[u & 0xFF], 1u);
    u = __float_as_uint(v.w); if ((u >> 8) == pfx) atomicAdd(&h[u & 0xFF], 1u);
  }
  __syncthreads();
  if (threadIdx.x < 256 && h[threadIdx.x]) atomicAdd(&hist[threadIdx.x], h[threadIdx.x]);
}

// -------------------- parallel rank-select --------------------
template<int NB>
__global__ __launch_bounds__(256) void k_sel(const unsigned* __restrict__ hist,
                                             Ctrl* c, int pass) {
  __shared__ unsigned sts[256];
  int t = threadIdx.x;
  unsigned K = (pass == 0) ? TOPK_TOTAL : (pass == 1 ? c->rank1 : c->rank2);
  constexpr int PER = NB / 256;
  unsigned h[PER];
  unsigned ts = 0;
#pragma unroll
  for (int i = 0; i < PER; ++i) { h[i] = hist[t * PER + i]; ts += h[i]; }
  sts[t] = ts;
  __syncthreads();
  unsigned suf = 0;
  for (int j = t + 1; j < 256; ++j) suf += sts[j];
  if (suf < K && K <= suf + ts) {
    unsigned cum = suf;
    for (int i = PER - 1; i >= 0; --i) {
      unsigned n = h[i];
      if (cum + n >= K) {
        unsigned b = (unsigned)(t * PER + i);
        if (pass == 0)      { c->b0 = b; c->rank1 = K - cum; }
        else if (pass == 1) { c->b1 = b; c->rank2 = K - cum; }
        else {
          c->t_bits = (c->b0 << 20) | (c->b1 << 8) | b;
          c->count_ge = cum + n;
        }
        break;
      }
      cum += n;
    }
  }
}

// -------------------- fused: column counts + boundary candidates --------------------
__global__ void k_fused(const float4* __restrict__ acts, Ctrl* c,
                        unsigned* __restrict__ col_cnt, unsigned* __restrict__ cands) {
  unsigned tb = c->t_bits;
  float t = __uint_as_float(tb);
  float lo = t - MU, hi = t + MU;
  unsigned above = 0;
  int n4 = NTOT / 4;
  for (int i = blockIdx.x * blockDim.x + threadIdx.x; i < n4; i += gridDim.x * blockDim.x) {
    float4 fv = acts[i];
    int base = i * 4;
#pragma unroll
    for (int q = 0; q < 4; ++q) {
      float v = (q == 0) ? fv.x : (q == 1) ? fv.y : (q == 2) ? fv.z : fv.w;
      if (__float_as_uint(v) >= tb) atomicAdd(&col_cnt[(base + q) & (DICT - 1)], 1u);
      if (v > hi) above++;
      else if (v >= lo) {
        unsigned p = atomicAdd(&c->cand_cnt, 1u);
        if (p < CAND_CAP) cands[p] = (unsigned)(base + q);
      }
    }
  }
  if (above) atomicAdd(&c->above_cnt, above);
}

// -------------------- fp64 boundary value (one block per candidate) --------------------
__global__ __launch_bounds__(256) void k_refine_v(
    const float* __restrict__ x_in, const float* __restrict__ W_enc,
    const float* __restrict__ b_enc, const float* __restrict__ b_dec,
    const Ctrl* __restrict__ c, const unsigned* __restrict__ cands,
    const double* __restrict__ rmean_d, const double* __restrict__ rinv_d,
    double* __restrict__ v64) {
  unsigned cc = c->cand_cnt;
  if (cc > CAND_CAP) return;            // fallback: keep fp32 decisions
  int i = blockIdx.x;
  if (i >= (int)cc) return;
  unsigned idx = cands[i];
  int r = (int)(idx >> 14), j = (int)(idx & (DICT - 1));
  double m = rmean_d[r], inv = rinv_d[r];
  const float* xr = x_in + (size_t)r * DDIM;
  int t = threadIdx.x;
  double acc = 0.0;
  for (int q = t; q < DDIM; q += 256)
    acc += (((double)xr[q] - m) * inv - (double)b_dec[q]) * (double)W_enc[(size_t)q * DICT + j];
  __shared__ double sd[256];
  sd[t] = acc;
  __syncthreads();
  for (int o = 128; o; o >>= 1) { if (t < o) sd[t] += sd[t + o]; __syncthreads(); }
  if (t == 0) v64[i] = sd[0] + (double)b_enc[j];
}

// -------------------- apply fp64 ranks: demote/promote (1 small block) --------------------
__global__ __launch_bounds__(256) void k_refine_apply(
    float* __restrict__ acts, Ctrl* c, unsigned* __restrict__ col_cnt,
    const unsigned* __restrict__ cands, const double* __restrict__ v64,
    unsigned* __restrict__ promo) {
  unsigned cc = c->cand_cnt;
  if (cc > CAND_CAP) return;
  int n = (int)cc;
  unsigned tb = c->t_bits;
  int Kp = (int)(TOPK_TOTAL - c->above_cnt);
  __shared__ double sv[CAND_CAP];
  __shared__ unsigned sidx[CAND_CAP];
  int t = threadIdx.x;
  for (int i = t; i < n; i += 256) { sv[i] = v64[i]; sidx[i] = cands[i]; }
  __syncthreads();
  for (int i = t; i < n; i += 256) {
    double my = sv[i];
    unsigned idx = sidx[i];
    int rank = 0;
    for (int s = 0; s < n; ++s)
      rank += (sv[s] > my || (sv[s] == my && sidx[s] < idx)) ? 1 : 0;
    bool sel64 = (rank < Kp);
    int j = (int)(idx & (DICT - 1));
    float v32 = acts[idx];
    bool sel32 = (__float_as_uint(v32) >= tb);
    if (sel32 && !sel64) {               // demote
      acts[idx] = 0.0f;
      atomicSub(&col_cnt[j], 1u);
    } else if (!sel32 && sel64) {        // promote
      unsigned p = atomicAdd(&c->promo_cnt, 1u);
      if (p < PROMO_CAP) {
        promo[p * 3 + 0] = idx >> 14;
        promo[p * 3 + 1] = (unsigned)j;
        promo[p * 3 + 2] = __float_as_uint(v32);
      }
      atomicAdd(&col_cnt[j], 1u);
    }
  }
}

// -------------------- dead bookkeeping --------------------
__global__ void k_dead(const int* __restrict__ nba_in, const unsigned* __restrict__ col_cnt,
                       Scal* sc, unsigned* __restrict__ deadlist, float* __restrict__ nba_out) {
  int j = blockIdx.x * blockDim.x + threadIdx.x;
  if (j >= DICT) return;
  int nn = (col_cnt[j] > 0) ? 0 : (nba_in[j] + 1);
  nba_out[j] = (float)nn;
  if (nn >= NDEAD_THR) { unsigned p = atomicAdd(&sc->dead_cnt, 1u); deadlist[p] = (unsigned)j; }
  if (nn > NDEAD_THR) atomicAdd(&sc->num_dead, 1u);
}

// -------------------- aux decode (dead columns only) --------------------
__global__ __launch_bounds__(256) void k_aux(
    const float* __restrict__ acts_dense, const float* __restrict__ W_dec,
    const Scal* __restrict__ sc, const unsigned* __restrict__ deadlist,
    float* __restrict__ y_pred_aux) {
  int r = blockIdx.y;
  int cidx = blockIdx.x * 256 + threadIdx.x;
  __shared__ float sv[256];
  __shared__ unsigned sj[256];
  int Dn = (int)sc->dead_cnt;
  float s = 0.0f;
  for (int base = 0; base < Dn; base += 256) {
    int n = min(256, Dn - base);
    __syncthreads();
    if (threadIdx.x < n) {
      unsigned j = deadlist[base + threadIdx.x];
      sj[threadIdx.x] = j;
      sv[threadIdx.x] = acts_dense[(size_t)r * DICT + j];
    }
    __syncthreads();
    for (int i = 0; i < n; ++i)
      s = fmaf(sv[i], W_dec[(size_t)sj[i] * DDIM + cidx], s);
  }
  y_pred_aux[(size_t)r * DDIM + cidx] = s;
}

// -------------------- per-row: sparsify + decode + losses --------------------
__global__ __launch_bounds__(256) void k_row(
    float* __restrict__ acts, const float* __restrict__ W_dec,
    const float* __restrict__ b_dec, const float* __restrict__ y_proc,
    const float* __restrict__ y_mean, const float* __restrict__ y_std,
    const float* __restrict__ y_pred_aux, const Ctrl* __restrict__ ctrl,
    const unsigned* __restrict__ promo,
    Scal* sc, float* __restrict__ y_pred_out) {
  int r = blockIdx.x, t = threadIdx.x;
  __shared__ int s_idx[2048];
  __shared__ float s_val[2048];
  __shared__ int s_cnt;
  __shared__ float red[4];
  if (t == 0) s_cnt = 0;
  __syncthreads();
  unsigned tb = ctrl->t_bits;
  float l1p = 0.0f;
  float* arow = acts + (size_t)r * DICT;
  for (int i = t; i < DICT; i += 256) {
    float v = arow[i];
    if (__float_as_uint(v) >= tb) {
      int p = atomicAdd(&s_cnt, 1);
      if (p < 2048) { s_idx[p] = i; s_val[p] = v; }
      l1p += v;
    } else {
      arow[i] = 0.0f;
    }
  }
  __syncthreads();
  // promoted elements (fp64-selected but below fp32 threshold)
  if (t == 0) {
    int pc = (int)min(ctrl->promo_cnt, (unsigned)PROMO_CAP);
    for (int p = 0; p < pc; ++p) {
      if ((int)promo[p * 3 + 0] == r) {
        int cpos = (int)promo[p * 3 + 1];
        float v = __uint_as_float(promo[p * 3 + 2]);
        int q = s_cnt;
        if (q < 2048) { s_idx[q] = cpos; s_val[q] = v; s_cnt = q + 1; }
        arow[cpos] = v;
        l1p += v;
      }
    }
  }
  __syncthreads();
  int m = min(s_cnt, 2048);
  float l1tot = blk_sum(l1p, red);
  if (t == 0) {
    atomicAdd(&sc->l1_sum, l1tot);
    atomicAdd(&sc->l0_cnt, (unsigned)m);
  }
  float l2p = 0.0f, auxp = 0.0f;
  float ym = y_mean[r], ys = y_std[r];
  for (int cpos = t; cpos < DDIM; cpos += 256) {
    float accv = b_dec[cpos];
    for (int i = 0; i < m; ++i)
      accv = fmaf(s_val[i], W_dec[(size_t)s_idx[i] * DDIM + cpos], accv);
    float yp = y_proc[(size_t)r * DDIM + cpos];
    float d = accv - yp;
    l2p += d * d;
    float da = y_pred_aux[(size_t)r * DDIM + cpos] + d;
    auxp += da * da;
    y_pred_out[(size_t)r * DDIM + cpos] = accv * ys + ym;
  }
  float l2t = blk_sum(l2p, red);
  float auxt = blk_sum(auxp, red);
  if (t == 0) {
    atomicAdd(&sc->l2_sum, l2t);
    atomicAdd(&sc->aux_sum, auxt);
  }
}

// -------------------- finalize scalars --------------------
__global__ void k_fin(const Scal* __restrict__ sc, float* __restrict__ out_scal) {
  if (threadIdx.x == 0 && blockIdx.x == 0) {
    float inv_bd = 1.0f / (float)(BATCH * DDIM);
    float l2 = sc->l2_sum * inv_bd;
    float l0 = (float)sc->l0_cnt * (1.0f / BATCH);
    float l1 = sc->l1_sum * (1.0f / BATCH);
    float l1l = L1_COEFF * l1;
    float aux = sc->dead_cnt ? AUX_PENALTY * sc->aux_sum * inv_bd : 0.0f;
    out_scal[0] = l2 + l1l + aux;
    out_scal[1] = l2;
    out_scal[2] = l0;
    out_scal[3] = l1;
    out_scal[4] = l1l;
    out_scal[5] = aux;
    out_scal[6] = (float)sc->num_dead;
  }
}

extern "C" void kernel_launch(void* const* d_in, const int* in_sizes, int n_in,
                              void* d_out, int out_size, void* d_ws, size_t ws_size,
                              hipStream_t stream) {
  const float* x_in  = (const float*)d_in[0];
  const float* y_t   = (const float*)d_in[1];
  const float* W_enc = (const float*)d_in[2];
  const float* b_enc = (const float*)d_in[3];
  const float* W_dec = (const float*)d_in[4];
  const float* b_dec = (const float*)d_in[5];
  const int*   nba   = (const int*)d_in[6];

  float* out = (float*)d_out;
  float* acts = out + OFF_ACTS;
  float* ws = (float*)d_ws;
  unsigned* wsu = (unsigned*)d_ws;
  Ctrl* ctrl = (Ctrl*)(wsu + WS_CTRL);
  Scal* scal = (Scal*)(wsu + WS_SCAL);

  float* x_enc  = ws + WS_XENC;
  float* y_proc = ws + WS_YPROC;
  float* y_mean = ws + WS_YMEAN;
  float* y_std  = ws + WS_YSTD;
  float* y_aux  = ws + WS_AUX;
  double* rmean_d = (double*)(wsu + WS_RMEAN);
  double* rinv_d  = (double*)(wsu + WS_RINV);
  double* v64     = (double*)(wsu + WS_V64);

  k_init<<<(WS_ZERO_END + 255) / 256, 256, 0, stream>>>(wsu);
  k_norm<<<BATCH, 256, 0, stream>>>(x_in, y_t, b_dec, x_enc, y_proc, y_mean, y_std,
                                    rmean_d, rinv_d);
  k_gemm<<<dim3(DICT / BN, BATCH / BM), 256, 0, stream>>>(x_enc, W_enc, b_enc, acts);
  k_histA<<<2048, 256, 0, stream>>>((const float4*)acts, wsu + WS_HISTA);
  k_sel<4096><<<1, 256, 0, stream>>>(wsu + WS_HISTA, ctrl, 0);
  k_histB<<<2048, 256, 0, stream>>>((const float4*)acts, ctrl, wsu + WS_HISTB);
  k_sel<4096><<<1, 256, 0, stream>>>(wsu + WS_HISTB, ctrl, 1);
  k_histC<<<2048, 256, 0, stream>>>((const float4*)acts, ctrl, wsu + WS_HISTC);
  k_sel<256><<<1, 256, 0, stream>>>(wsu + WS_HISTC, ctrl, 2);
  k_fused<<<2048, 256, 0, stream>>>((const float4*)acts, ctrl, wsu + WS_COLCNT, wsu + WS_CANDS);
  k_refine_v<<<CAND_CAP, 256, 0, stream>>>(x_in, W_enc, b_enc, b_dec, ctrl,
                                           wsu + WS_CANDS, rmean_d, rinv_d, v64);
  k_refine_apply<<<1, 256, 0, stream>>>(acts, ctrl, wsu + WS_COLCNT, wsu + WS_CANDS, v64,
                                        wsu + WS_PROMO);
  k_dead<<<DICT / 256, 256, 0, stream>>>(nba, wsu + WS_COLCNT, scal, wsu + WS_CANDS,
                                         out + OFF_NBA);
  // NOTE: deadlist reuses WS_CANDS (candidates consumed by refine)
  k_aux<<<dim3(DDIM / 256, BATCH), 256, 0, stream>>>(acts, W_dec, scal, wsu + WS_CANDS, y_aux);
  k_row<<<BATCH, 256, 0, stream>>>(acts, W_dec, b_dec, y_proc, y_mean, y_std, y_aux,
                                   ctrl, wsu + WS_PROMO, scal, out + OFF_YPRED);
  k_fin<<<1, 64, 0, stream>>>(scal, out + OFF_SCAL);
}

// Round 8
// 824.416 us; speedup vs baseline: 1.9857x; 1.4391x over previous
//
#include <hip/hip_runtime.h>
#include <stdint.h>

#define BATCH 2048
#define DDIM 768
#define DICT 16384
#define NTOT (BATCH*DICT)
#define TOPK_TOTAL 65536
#define NDEAD_THR 15360
#define EPS 1e-5f
#define L1_COEFF 3.0e-4f
#define AUX_PENALTY 0.03125f
#define MU 1e-3f
#define CAND_CAP 2048
#define PROMO_CAP 64

typedef float f32x4 __attribute__((ext_vector_type(4)));
typedef short bf16x8 __attribute__((ext_vector_type(8)));

// ---- d_out layout (floats) ----
#define OFF_YPRED 0
#define OFF_ACTS  (BATCH*DDIM)
#define OFF_SCAL  (OFF_ACTS + (size_t)NTOT)
#define OFF_NBA   (OFF_SCAL + 7)

// ---- ws layout (32-bit units) ----
#define WS_HISTA 0
#define WS_HISTB 4096          // reused as WS_V64 (2048 doubles) after selB
#define WS_HISTC 8192
#define WS_CTRL  8448
#define WS_SCAL  8464
#define WS_COLCNT 8480
#define WS_ZERO_END 24864
#define WS_CANDS 24864         // reused as deadlist after refine
#define WS_PROMO 26912
#define WS_XENC  27104
#define WS_YPROC (WS_XENC + BATCH*DDIM)
#define WS_YMEAN (WS_YPROC + BATCH*DDIM)
#define WS_YSTD  (WS_YMEAN + BATCH)
#define WS_AUX   (WS_YSTD + BATCH)
#define WS_RMEAN (WS_AUX + BATCH*DDIM)
#define WS_RINV  (WS_RMEAN + 2*BATCH)
#define WS_V64   WS_HISTB
// bf16 split planes (ushort data, offsets in u32 units)
#define WS_AH    (WS_RINV + 2*BATCH)            // 2048*768 ushort = 786432 u32
#define WS_AL    (WS_AH + BATCH*DDIM/2)
#define WS_WTH   (WS_AL + BATCH*DDIM/2)          // 16384*768 ushort = 6291456 u32
#define WS_WTL   (WS_WTH + DICT*DDIM/2)
#define WS_END   (WS_WTL + DICT*DDIM/2)
#define WS_NEED_BYTES ((size_t)WS_END * 4)

struct Ctrl {
  unsigned b0, rank1, b1, rank2, t_bits, count_ge;
  unsigned cand_cnt, above_cnt, promo_cnt, pad0, pad1, pad2, pad3, pad4, pad5, pad6;
};
struct Scal {
  float l1_sum, l2_sum, aux_sum;
  unsigned l0_cnt, num_dead, dead_cnt, pad0, pad1;
};

__device__ __forceinline__ float blk_sum(float v, float* sh) {
#pragma unroll
  for (int o = 32; o; o >>= 1) v += __shfl_down(v, o, 64);
  int lane = threadIdx.x & 63, w = threadIdx.x >> 6;
  __syncthreads();
  if (lane == 0) sh[w] = v;
  __syncthreads();
  return sh[0] + sh[1] + sh[2] + sh[3];
}

__device__ __forceinline__ double blk_sum_d(double v, double* shd) {
#pragma unroll
  for (int o = 32; o; o >>= 1) v += __shfl_down(v, o, 64);
  int lane = threadIdx.x & 63, w = threadIdx.x >> 6;
  __syncthreads();
  if (lane == 0) shd[w] = v;
  __syncthreads();
  return shd[0] + shd[1] + shd[2] + shd[3];
}

// bf16 round-to-nearest-even (finite inputs)
__device__ __forceinline__ unsigned short bfh(float x) {
  unsigned u = __float_as_uint(x);
  return (unsigned short)((u + 0x7FFFu + ((u >> 16) & 1u)) >> 16);
}

// -------------------- init --------------------
__global__ void k_init(unsigned* ws) {
  int i = blockIdx.x * blockDim.x + threadIdx.x;
  if (i < WS_ZERO_END) ws[i] = 0u;
}

// -------------------- normalize x,y (fp32) + fp64 row-stats + bf16 split of x_enc ----
__global__ __launch_bounds__(256) void k_norm(
    const float* __restrict__ x_in, const float* __restrict__ y_t,
    const float* __restrict__ b_dec,
    float* __restrict__ x_enc, float* __restrict__ y_proc,
    float* __restrict__ y_mean, float* __restrict__ y_std,
    double* __restrict__ rmean_d, double* __restrict__ rinv_d,
    unsigned short* __restrict__ ah, unsigned short* __restrict__ al) {
  int r = blockIdx.x, t = threadIdx.x;
  __shared__ float red[4];
  __shared__ double redd[4];
  const float* xr = x_in + (size_t)r * DDIM;
  float v0 = xr[t], v1 = xr[t + 256], v2 = xr[t + 512];
  float s = blk_sum(v0 + v1 + v2, red);
  float mean = s * (1.0f / DDIM);
  float d0 = v0 - mean, d1 = v1 - mean, d2 = v2 - mean;
  float ss = blk_sum(d0*d0 + d1*d1 + d2*d2, red);
  float stdv = sqrtf(ss * (1.0f / (DDIM - 1)));
  float inv = 1.0f / (stdv + EPS);
  float xe0 = d0 * inv - b_dec[t];
  float xe1 = d1 * inv - b_dec[t + 256];
  float xe2 = d2 * inv - b_dec[t + 512];
  float* xe = x_enc + (size_t)r * DDIM;
  xe[t] = xe0; xe[t + 256] = xe1; xe[t + 512] = xe2;
  if (ah) {
    size_t b = (size_t)r * DDIM;
    unsigned short h0 = bfh(xe0), h1 = bfh(xe1), h2 = bfh(xe2);
    ah[b + t] = h0; ah[b + t + 256] = h1; ah[b + t + 512] = h2;
    al[b + t]       = bfh(xe0 - __uint_as_float((unsigned)h0 << 16));
    al[b + t + 256] = bfh(xe1 - __uint_as_float((unsigned)h1 << 16));
    al[b + t + 512] = bfh(xe2 - __uint_as_float((unsigned)h2 << 16));
  }
  // fp64 stats for refine
  double sd = blk_sum_d((double)v0 + (double)v1 + (double)v2, redd);
  double md = sd * (1.0 / DDIM);
  double e0 = (double)v0 - md, e1 = (double)v1 - md, e2 = (double)v2 - md;
  double ssd = blk_sum_d(e0*e0 + e1*e1 + e2*e2, redd);
  double invd = 1.0 / (sqrt(ssd * (1.0 / (DDIM - 1))) + 1e-5);
  if (t == 0) { rmean_d[r] = md; rinv_d[r] = invd; }
  // y
  const float* yr = y_t + (size_t)r * DDIM;
  v0 = yr[t]; v1 = yr[t + 256]; v2 = yr[t + 512];
  s = blk_sum(v0 + v1 + v2, red);
  mean = s * (1.0f / DDIM);
  d0 = v0 - mean; d1 = v1 - mean; d2 = v2 - mean;
  ss = blk_sum(d0*d0 + d1*d1 + d2*d2, red);
  stdv = sqrtf(ss * (1.0f / (DDIM - 1)));
  inv = 1.0f / (stdv + EPS);
  float* yp = y_proc + (size_t)r * DDIM;
  yp[t] = d0 * inv; yp[t + 256] = d1 * inv; yp[t + 512] = d2 * inv;
  if (t == 0) { y_mean[r] = mean; y_std[r] = stdv; }
}

// -------------------- W transpose + bf16 split: W[768][16384] -> Wt{h,l}[16384][768] ----
__global__ __launch_bounds__(256) void k_splitw(
    const float* __restrict__ W,
    unsigned short* __restrict__ wth, unsigned short* __restrict__ wtl) {
  __shared__ __align__(16) float sw[64][68];
  int k0 = blockIdx.x * 64, n0 = blockIdx.y * 64;
  int t = threadIdx.x;
  {
    int kr = t >> 2, cq = (t & 3) * 16;
    const float* src = W + (size_t)(k0 + kr) * DICT + n0 + cq;
#pragma unroll
    for (int j = 0; j < 4; ++j)
      *(f32x4*)&sw[kr][cq + j * 4] = *(const f32x4*)(src + j * 4);
  }
  __syncthreads();
  {
    int nr = t & 63, kq = (t >> 6) * 16;
    unsigned short h8[16], l8[16];
#pragma unroll
    for (int i = 0; i < 16; ++i) {
      float x = sw[kq + i][nr];
      unsigned short h = bfh(x);
      h8[i] = h;
      l8[i] = bfh(x - __uint_as_float((unsigned)h << 16));
    }
    size_t base = (size_t)(n0 + nr) * DDIM + k0 + kq;
    *(uint4*)&wth[base]     = *(uint4*)&h8[0];
    *(uint4*)&wth[base + 8] = *(uint4*)&h8[8];
    *(uint4*)&wtl[base]     = *(uint4*)&l8[0];
    *(uint4*)&wtl[base + 8] = *(uint4*)&l8[8];
  }
}

// -------------------- bf16x3 MFMA encoder GEMM --------------------
// C[2048x16384] = relu(A*W + b_enc), A/W pre-split into bf16 hi/lo (Wt transposed [N][K])
#define PK 40   // padded LDS row stride in shorts (80B; spreads banks, 16B aligned)
__global__ __launch_bounds__(256) void k_gemm_mfma(
    const unsigned short* __restrict__ Ah, const unsigned short* __restrict__ Al,
    const unsigned short* __restrict__ Bh, const unsigned short* __restrict__ Bl,
    const float* __restrict__ b_enc, float* __restrict__ C) {
  __shared__ __align__(16) unsigned short lds[4 * 128 * PK];
  const int LAH = 0, LAL = 128 * PK, LBH = 2 * 128 * PK, LBL = 3 * 128 * PK;
  int t = threadIdx.x;
  int n0 = blockIdx.x * 128, m0 = blockIdx.y * 128;
  int w = t >> 6, l = t & 63;
  int wm = (w & 1) * 64, wn = (w >> 1) * 64;
  int r16 = l & 15, koct = l >> 4;
  f32x4 zz = {0.f, 0.f, 0.f, 0.f};
  f32x4 acc[4][4];
#pragma unroll
  for (int mi = 0; mi < 4; ++mi)
#pragma unroll
    for (int ni = 0; ni < 4; ++ni) acc[mi][ni] = zz;

  int srow = t >> 2;             // 0..63
  int sq = (t & 3) * 8;          // short offset within 32-k row (quarter = 16B)
  for (int k0 = 0; k0 < DDIM; k0 += 32) {
    uint4 ra0 = *(const uint4*)&Ah[(size_t)(m0 + srow) * DDIM + k0 + sq];
    uint4 ra1 = *(const uint4*)&Ah[(size_t)(m0 + srow + 64) * DDIM + k0 + sq];
    uint4 rb0 = *(const uint4*)&Al[(size_t)(m0 + srow) * DDIM + k0 + sq];
    uint4 rb1 = *(const uint4*)&Al[(size_t)(m0 + srow + 64) * DDIM + k0 + sq];
    uint4 rc0 = *(const uint4*)&Bh[(size_t)(n0 + srow) * DDIM + k0 + sq];
    uint4 rc1 = *(const uint4*)&Bh[(size_t)(n0 + srow + 64) * DDIM + k0 + sq];
    uint4 rd0 = *(const uint4*)&Bl[(size_t)(n0 + srow) * DDIM + k0 + sq];
    uint4 rd1 = *(const uint4*)&Bl[(size_t)(n0 + srow + 64) * DDIM + k0 + sq];
    __syncthreads();   // previous compute done before overwriting LDS
    *(uint4*)&lds[LAH + srow * PK + sq] = ra0;
    *(uint4*)&lds[LAH + (srow + 64) * PK + sq] = ra1;
    *(uint4*)&lds[LAL + srow * PK + sq] = rb0;
    *(uint4*)&lds[LAL + (srow + 64) * PK + sq] = rb1;
    *(uint4*)&lds[LBH + srow * PK + sq] = rc0;
    *(uint4*)&lds[LBH + (srow + 64) * PK + sq] = rc1;
    *(uint4*)&lds[LBL + srow * PK + sq] = rd0;
    *(uint4*)&lds[LBL + (srow + 64) * PK + sq] = rd1;
    __syncthreads();
    bf16x8 bhf[4], blf[4];
#pragma unroll
    for (int ni = 0; ni < 4; ++ni) {
      int rowb = wn + ni * 16 + r16;
      bhf[ni] = *(bf16x8*)&lds[LBH + rowb * PK + koct * 8];
      blf[ni] = *(bf16x8*)&lds[LBL + rowb * PK + koct * 8];
    }
#pragma unroll
    for (int mi = 0; mi < 4; ++mi) {
      int rowa = wm + mi * 16 + r16;
      bf16x8 ahf = *(bf16x8*)&lds[LAH + rowa * PK + koct * 8];
      bf16x8 alf = *(bf16x8*)&lds[LAL + rowa * PK + koct * 8];
#pragma unroll
      for (int ni = 0; ni < 4; ++ni) {
        acc[mi][ni] = __builtin_amdgcn_mfma_f32_16x16x32_bf16(ahf, bhf[ni], acc[mi][ni], 0, 0, 0);
        acc[mi][ni] = __builtin_amdgcn_mfma_f32_16x16x32_bf16(ahf, blf[ni], acc[mi][ni], 0, 0, 0);
        acc[mi][ni] = __builtin_amdgcn_mfma_f32_16x16x32_bf16(alf, bhf[ni], acc[mi][ni], 0, 0, 0);
      }
    }
  }
  // epilogue: C/D layout col = l&15, row = (l>>4)*4 + r  [m89/m91]
#pragma unroll
  for (int ni = 0; ni < 4; ++ni) {
    int coln = n0 + wn + ni * 16 + r16;
    float be = b_enc[coln];
#pragma unroll
    for (int mi = 0; mi < 4; ++mi) {
      int rowb = m0 + wm + mi * 16 + koct * 4;
      f32x4 v = acc[mi][ni];
#pragma unroll
      for (int r = 0; r < 4; ++r) {
        float o = v[r] + be;
        C[(size_t)(rowb + r) * DICT + coln] = o > 0.0f ? o : 0.0f;
      }
    }
  }
}

// -------------------- fp32 encoder GEMM (fallback when ws too small) ----------
#define BM 128
#define BN 128
#define BKF 16
#define BSTR (BKF*8 + 4)
__global__ __launch_bounds__(256) void k_gemm_f32(
    const float* __restrict__ A, const float* __restrict__ B,
    const float* __restrict__ b_enc, float* __restrict__ C) {
  __shared__ float As[BKF][BM];
  __shared__ float Bs[16 * BSTR];
  int m0 = blockIdx.y * BM, n0 = blockIdx.x * BN;
  int t = threadIdx.x;
  float acc[8][8] = {};
  int am = t >> 1, aq = (t & 1) * 8;
  int bk = t >> 5, bc = (t & 31) * 4;
  const float* Aptr = A + (size_t)(m0 + am) * DDIM + aq;
  const float* Bptr = B + (size_t)bk * DICT + n0 + bc;
  int tm = (t >> 4) * 8, tn8 = (t & 15);
  int bs_w0 = (bc >> 3) * BSTR + bk * 8 + (bc & 7);
  int bs_w1 = (bc >> 3) * BSTR + (bk + 8) * 8 + (bc & 7);
  for (int k0 = 0; k0 < DDIM; k0 += BKF) {
    float4 a0 = *(const float4*)(Aptr + k0);
    float4 a1 = *(const float4*)(Aptr + k0 + 4);
    float4 b0 = *(const float4*)(Bptr + (size_t)k0 * DICT);
    float4 b1 = *(const float4*)(Bptr + (size_t)(k0 + 8) * DICT);
    As[aq + 0][am] = a0.x; As[aq + 1][am] = a0.y;
    As[aq + 2][am] = a0.z; As[aq + 3][am] = a0.w;
    As[aq + 4][am] = a1.x; As[aq + 5][am] = a1.y;
    As[aq + 6][am] = a1.z; As[aq + 7][am] = a1.w;
    *(float4*)&Bs[bs_w0] = b0;
    *(float4*)&Bs[bs_w1] = b1;
    __syncthreads();
#pragma unroll
    for (int k = 0; k < BKF; ++k) {
      float a[8], b[8];
      *(float4*)(a)     = *(float4*)&As[k][tm];
      *(float4*)(a + 4) = *(float4*)&As[k][tm + 4];
      const float* bp = &Bs[tn8 * BSTR + k * 8];
      *(float4*)(b)     = *(const float4*)(bp);
      *(float4*)(b + 4) = *(const float4*)(bp + 4);
#pragma unroll
      for (int i = 0; i < 8; ++i)
#pragma unroll
        for (int j = 0; j < 8; ++j)
          acc[i][j] = fmaf(a[i], b[j], acc[i][j]);
    }
    __syncthreads();
  }
  int tn = tn8 * 8;
  float be[8];
  *(float4*)(be)     = *(const float4*)&b_enc[n0 + tn];
  *(float4*)(be + 4) = *(const float4*)&b_enc[n0 + tn + 4];
#pragma unroll
  for (int i = 0; i < 8; ++i) {
    size_t row = (size_t)(m0 + tm + i);
    float o[8];
#pragma unroll
    for (int j = 0; j < 8; ++j) {
      float v = acc[i][j] + be[j];
      o[j] = v > 0.0f ? v : 0.0f;
    }
    *(float4*)&C[row * DICT + n0 + tn]     = *(float4*)(o);
    *(float4*)&C[row * DICT + n0 + tn + 4] = *(float4*)(o + 4);
  }
}

// -------------------- radix-select histograms (3 passes) --------------------
__global__ void k_histA(const float4* __restrict__ acts, unsigned* __restrict__ hist) {
  __shared__ unsigned h[4096];
  for (int i = threadIdx.x; i < 4096; i += 256) h[i] = 0;
  __syncthreads();
  unsigned zc = 0;
  int n4 = NTOT / 4;
  for (int i = blockIdx.x * blockDim.x + threadIdx.x; i < n4; i += gridDim.x * blockDim.x) {
    float4 v = acts[i];
    unsigned u;
    u = __float_as_uint(v.x); if (u) atomicAdd(&h[u >> 20], 1u); else zc++;
    u = __float_as_uint(v.y); if (u) atomicAdd(&h[u >> 20], 1u); else zc++;
    u = __float_as_uint(v.z); if (u) atomicAdd(&h[u >> 20], 1u); else zc++;
    u = __float_as_uint(v.w); if (u) atomicAdd(&h[u >> 20], 1u); else zc++;
  }
  if (zc) atomicAdd(&h[0], zc);
  __syncthreads();
  for (int i = threadIdx.x; i < 4096; i += 256) if (h[i]) atomicAdd(&hist[i], h[i]);
}

__global__ void k_histB(const float4* __restrict__ acts, const Ctrl* __restrict__ c,
                        unsigned* __restrict__ hist) {
  __shared__ unsigned h[4096];
  for (int i = threadIdx.x; i < 4096; i += 256) h[i] = 0;
  __syncthreads();
  unsigned b0 = c->b0;
  int n4 = NTOT / 4;
  for (int i = blockIdx.x * blockDim.x + threadIdx.x; i < n4; i += gridDim.x * blockDim.x) {
    float4 v = acts[i];
    unsigned u;
    u = __float_as_uint(v.x); if ((u >> 20) == b0) atomicAdd(&h[(u >> 8) & 0xFFF], 1u);
    u = __float_as_uint(v.y); if ((u >> 20) == b0) atomicAdd(&h[(u >> 8) & 0xFFF], 1u);
    u = __float_as_uint(v.z); if ((u >> 20) == b0) atomicAdd(&h[(u >> 8) & 0xFFF], 1u);
    u = __float_as_uint(v.w); if ((u >> 20) == b0) atomicAdd(&h[(u >> 8) & 0xFFF], 1u);
  }
  __syncthreads();
  for (int i = threadIdx.x; i < 4096; i += 256) if (h[i]) atomicAdd(&hist[i], h[i]);
}

__global__ void k_histC(const float4* __restrict__ acts, const Ctrl* __restrict__ c,
                        unsigned* __restrict__ hist) {
  __shared__ unsigned h[256];
  if (threadIdx.x < 256) h[threadIdx.x] = 0;
  __syncthreads();
  unsigned pfx = (c->b0 << 12) | c->b1;
  int n4 = NTOT / 4;
  for (int i = blockIdx.x * blockDim.x + threadIdx.x; i < n4; i += gridDim.x * blockDim.x) {
    float4 v = acts[i];
    unsigned u;
    u = __float_as_uint(v.x); if ((u >> 8) == pfx) atomicAdd(&h[u & 0xFF], 1u);
    u = __float_as_uint(v.y); if ((u >> 8) == pfx) atomicAdd(&h[u & 0xFF], 1u);
    u = __float_as_uint(v.z); if ((u >> 8) == pfx) atomicAdd(&h[u & 0xFF], 1u);
    u = __float_as_uint(v.w); if ((u >> 8) == pfx) atomicAdd(&h[u & 0xFF], 1u);
  }
  __syncthreads();
  if (threadIdx.x < 256 && h[threadIdx.x]) atomicAdd(&hist[threadIdx.x], h[threadIdx.x]);
}

// -------------------- parallel rank-select --------------------
template<int NB>
__global__ __launch_bounds__(256) void k_sel(const unsigned* __restrict__ hist,
                                             Ctrl* c, int pass) {
  __shared__ unsigned sts[256];
  int t = threadIdx.x;
  unsigned K = (pass == 0) ? TOPK_TOTAL : (pass == 1 ? c->rank1 : c->rank2);
  constexpr int PER = NB / 256;
  unsigned h[PER];
  unsigned ts = 0;
#pragma unroll
  for (int i = 0; i < PER; ++i) { h[i] = hist[t * PER + i]; ts += h[i]; }
  sts[t] = ts;
  __syncthreads();
  unsigned suf = 0;
  for (int j = t + 1; j < 256; ++j) suf += sts[j];
  if (suf < K && K <= suf + ts) {
    unsigned cum = suf;
    for (int i = PER - 1; i >= 0; --i) {
      unsigned n = h[i];
      if (cum + n >= K) {
        unsigned b = (unsigned)(t * PER + i);
        if (pass == 0)      { c->b0 = b; c->rank1 = K - cum; }
        else if (pass == 1) { c->b1 = b; c->rank2 = K - cum; }
        else {
          c->t_bits = (c->b0 << 20) | (c->b1 << 8) | b;
          c->count_ge = cum + n;
        }
        break;
      }
      cum += n;
    }
  }
}

// -------------------- fused: column counts + boundary candidates --------------------
__global__ void k_fused(const float4* __restrict__ acts, Ctrl* c,
                        unsigned* __restrict__ col_cnt, unsigned* __restrict__ cands) {
  unsigned tb = c->t_bits;
  float t = __uint_as_float(tb);
  float lo = t - MU, hi = t + MU;
  unsigned above = 0;
  int n4 = NTOT / 4;
  for (int i = blockIdx.x * blockDim.x + threadIdx.x; i < n4; i += gridDim.x * blockDim.x) {
    float4 fv = acts[i];
    int base = i * 4;
#pragma unroll
    for (int q = 0; q < 4; ++q) {
      float v = (q == 0) ? fv.x : (q == 1) ? fv.y : (q == 2) ? fv.z : fv.w;
      if (__float_as_uint(v) >= tb) atomicAdd(&col_cnt[(base + q) & (DICT - 1)], 1u);
      if (v > hi) above++;
      else if (v >= lo) {
        unsigned p = atomicAdd(&c->cand_cnt, 1u);
        if (p < CAND_CAP) cands[p] = (unsigned)(base + q);
      }
    }
  }
  if (above) atomicAdd(&c->above_cnt, above);
}

// -------------------- fp64 boundary value (one block per candidate) --------------------
__global__ __launch_bounds__(256) void k_refine_v(
    const float* __restrict__ x_in, const float* __restrict__ W_enc,
    const float* __restrict__ b_enc, const float* __restrict__ b_dec,
    const Ctrl* __restrict__ c, const unsigned* __restrict__ cands,
    const double* __restrict__ rmean_d, const double* __restrict__ rinv_d,
    double* __restrict__ v64) {
  unsigned cc = c->cand_cnt;
  if (cc > CAND_CAP) return;
  int i = blockIdx.x;
  if (i >= (int)cc) return;
  unsigned idx = cands[i];
  int r = (int)(idx >> 14), j = (int)(idx & (DICT - 1));
  double m = rmean_d[r], inv = rinv_d[r];
  const float* xr = x_in + (size_t)r * DDIM;
  int t = threadIdx.x;
  double acc = 0.0;
  for (int q = t; q < DDIM; q += 256)
    acc += (((double)xr[q] - m) * inv - (double)b_dec[q]) * (double)W_enc[(size_t)q * DICT + j];
  __shared__ double sd[256];
  sd[t] = acc;
  __syncthreads();
  for (int o = 128; o; o >>= 1) { if (t < o) sd[t] += sd[t + o]; __syncthreads(); }
  if (t == 0) v64[i] = sd[0] + (double)b_enc[j];
}

// -------------------- apply fp64 ranks: demote/promote --------------------
__global__ __launch_bounds__(256) void k_refine_apply(
    float* __restrict__ acts, Ctrl* c, unsigned* __restrict__ col_cnt,
    const unsigned* __restrict__ cands, const double* __restrict__ v64,
    unsigned* __restrict__ promo) {
  unsigned cc = c->cand_cnt;
  if (cc > CAND_CAP) return;
  int n = (int)cc;
  unsigned tb = c->t_bits;
  int Kp = (int)(TOPK_TOTAL - c->above_cnt);
  __shared__ double sv[CAND_CAP];
  __shared__ unsigned sidx[CAND_CAP];
  int t = threadIdx.x;
  for (int i = t; i < n; i += 256) { sv[i] = v64[i]; sidx[i] = cands[i]; }
  __syncthreads();
  for (int i = t; i < n; i += 256) {
    double my = sv[i];
    unsigned idx = sidx[i];
    int rank = 0;
    for (int s = 0; s < n; ++s)
      rank += (sv[s] > my || (sv[s] == my && sidx[s] < idx)) ? 1 : 0;
    bool sel64 = (rank < Kp);
    int j = (int)(idx & (DICT - 1));
    float v32 = acts[idx];
    bool sel32 = (__float_as_uint(v32) >= tb);
    if (sel32 && !sel64) {
      acts[idx] = 0.0f;
      atomicSub(&col_cnt[j], 1u);
    } else if (!sel32 && sel64) {
      unsigned p = atomicAdd(&c->promo_cnt, 1u);
      if (p < PROMO_CAP) {
        promo[p * 3 + 0] = idx >> 14;
        promo[p * 3 + 1] = (unsigned)j;
        promo[p * 3 + 2] = __float_as_uint(v32);
      }
      atomicAdd(&col_cnt[j], 1u);
    }
  }
}

// -------------------- dead bookkeeping --------------------
__global__ void k_dead(const int* __restrict__ nba_in, const unsigned* __restrict__ col_cnt,
                       Scal* sc, unsigned* __restrict__ deadlist, float* __restrict__ nba_out) {
  int j = blockIdx.x * blockDim.x + threadIdx.x;
  if (j >= DICT) return;
  int nn = (col_cnt[j] > 0) ? 0 : (nba_in[j] + 1);
  nba_out[j] = (float)nn;
  if (nn >= NDEAD_THR) { unsigned p = atomicAdd(&sc->dead_cnt, 1u); deadlist[p] = (unsigned)j; }
  if (nn > NDEAD_THR) atomicAdd(&sc->num_dead, 1u);
}

// -------------------- aux decode (dead columns only) --------------------
__global__ __launch_bounds__(256) void k_aux(
    const float* __restrict__ acts_dense, const float* __restrict__ W_dec,
    const Scal* __restrict__ sc, const unsigned* __restrict__ deadlist,
    float* __restrict__ y_pred_aux) {
  int r = blockIdx.y;
  int cidx = blockIdx.x * 256 + threadIdx.x;
  __shared__ float sv[256];
  __shared__ unsigned sj[256];
  int Dn = (int)sc->dead_cnt;
  float s = 0.0f;
  for (int base = 0; base < Dn; base += 256) {
    int n = min(256, Dn - base);
    __syncthreads();
    if (threadIdx.x < n) {
      unsigned j = deadlist[base + threadIdx.x];
      sj[threadIdx.x] = j;
      sv[threadIdx.x] = acts_dense[(size_t)r * DICT + j];
    }
    __syncthreads();
    for (int i = 0; i < n; ++i)
      s = fmaf(sv[i], W_dec[(size_t)sj[i] * DDIM + cidx], s);
  }
  y_pred_aux[(size_t)r * DDIM + cidx] = s;
}

// -------------------- per-row: sparsify + decode + losses --------------------
__global__ __launch_bounds__(256) void k_row(
    float* __restrict__ acts, const float* __restrict__ W_dec,
    const float* __restrict__ b_dec, const float* __restrict__ y_proc,
    const float* __restrict__ y_mean, const float* __restrict__ y_std,
    const float* __restrict__ y_pred_aux, const Ctrl* __restrict__ ctrl,
    const unsigned* __restrict__ promo,
    Scal* sc, float* __restrict__ y_pred_out) {
  int r = blockIdx.x, t = threadIdx.x;
  __shared__ int s_idx[2048];
  __shared__ float s_val[2048];
  __shared__ int s_cnt;
  __shared__ float red[4];
  if (t == 0) s_cnt = 0;
  __syncthreads();
  unsigned tb = ctrl->t_bits;
  float l1p = 0.0f;
  float* arow = acts + (size_t)r * DICT;
  for (int i = t; i < DICT; i += 256) {
    float v = arow[i];
    if (__float_as_uint(v) >= tb) {
      int p = atomicAdd(&s_cnt, 1);
      if (p < 2048) { s_idx[p] = i; s_val[p] = v; }
      l1p += v;
    } else {
      arow[i] = 0.0f;
    }
  }
  __syncthreads();
  if (t == 0) {
    int pc = (int)min(ctrl->promo_cnt, (unsigned)PROMO_CAP);
    for (int p = 0; p < pc; ++p) {
      if ((int)promo[p * 3 + 0] == r) {
        int cpos = (int)promo[p * 3 + 1];
        float v = __uint_as_float(promo[p * 3 + 2]);
        int q = s_cnt;
        if (q < 2048) { s_idx[q] = cpos; s_val[q] = v; s_cnt = q + 1; }
        arow[cpos] = v;
        l1p += v;
      }
    }
  }
  __syncthreads();
  int m = min(s_cnt, 2048);
  float l1tot = blk_sum(l1p, red);
  if (t == 0) {
    atomicAdd(&sc->l1_sum, l1tot);
    atomicAdd(&sc->l0_cnt, (unsigned)m);
  }
  float l2p = 0.0f, auxp = 0.0f;
  float ym = y_mean[r], ys = y_std[r];
  for (int cpos = t; cpos < DDIM; cpos += 256) {
    float accv = b_dec[cpos];
    for (int i = 0; i < m; ++i)
      accv = fmaf(s_val[i], W_dec[(size_t)s_idx[i] * DDIM + cpos], accv);
    float yp = y_proc[(size_t)r * DDIM + cpos];
    float d = accv - yp;
    l2p += d * d;
    float da = y_pred_aux[(size_t)r * DDIM + cpos] + d;
    auxp += da * da;
    y_pred_out[(size_t)r * DDIM + cpos] = accv * ys + ym;
  }
  float l2t = blk_sum(l2p, red);
  float auxt = blk_sum(auxp, red);
  if (t == 0) {
    atomicAdd(&sc->l2_sum, l2t);
    atomicAdd(&sc->aux_sum, auxt);
  }
}

// -------------------- finalize scalars --------------------
__global__ void k_fin(const Scal* __restrict__ sc, float* __restrict__ out_scal) {
  if (threadIdx.x == 0 && blockIdx.x == 0) {
    float inv_bd = 1.0f / (float)(BATCH * DDIM);
    float l2 = sc->l2_sum * inv_bd;
    float l0 = (float)sc->l0_cnt * (1.0f / BATCH);
    float l1 = sc->l1_sum * (1.0f / BATCH);
    float l1l = L1_COEFF * l1;
    float aux = sc->dead_cnt ? AUX_PENALTY * sc->aux_sum * inv_bd : 0.0f;
    out_scal[0] = l2 + l1l + aux;
    out_scal[1] = l2;
    out_scal[2] = l0;
    out_scal[3] = l1;
    out_scal[4] = l1l;
    out_scal[5] = aux;
    out_scal[6] = (float)sc->num_dead;
  }
}

extern "C" void kernel_launch(void* const* d_in, const int* in_sizes, int n_in,
                              void* d_out, int out_size, void* d_ws, size_t ws_size,
                              hipStream_t stream) {
  const float* x_in  = (const float*)d_in[0];
  const float* y_t   = (const float*)d_in[1];
  const float* W_enc = (const float*)d_in[2];
  const float* b_enc = (const float*)d_in[3];
  const float* W_dec = (const float*)d_in[4];
  const float* b_dec = (const float*)d_in[5];
  const int*   nba   = (const int*)d_in[6];

  float* out = (float*)d_out;
  float* acts = out + OFF_ACTS;
  float* ws = (float*)d_ws;
  unsigned* wsu = (unsigned*)d_ws;
  Ctrl* ctrl = (Ctrl*)(wsu + WS_CTRL);
  Scal* scal = (Scal*)(wsu + WS_SCAL);

  float* x_enc  = ws + WS_XENC;
  float* y_proc = ws + WS_YPROC;
  float* y_mean = ws + WS_YMEAN;
  float* y_std  = ws + WS_YSTD;
  float* y_aux  = ws + WS_AUX;
  double* rmean_d = (double*)(wsu + WS_RMEAN);
  double* rinv_d  = (double*)(wsu + WS_RINV);
  double* v64     = (double*)(wsu + WS_V64);

  const bool use_mfma = (ws_size >= WS_NEED_BYTES);
  unsigned short* ahp = use_mfma ? (unsigned short*)(wsu + WS_AH) : nullptr;
  unsigned short* alp = use_mfma ? (unsigned short*)(wsu + WS_AL) : nullptr;
  unsigned short* wth = (unsigned short*)(wsu + WS_WTH);
  unsigned short* wtl = (unsigned short*)(wsu + WS_WTL);

  k_init<<<(WS_ZERO_END + 255) / 256, 256, 0, stream>>>(wsu);
  k_norm<<<BATCH, 256, 0, stream>>>(x_in, y_t, b_dec, x_enc, y_proc, y_mean, y_std,
                                    rmean_d, rinv_d, ahp, alp);
  if (use_mfma) {
    k_splitw<<<dim3(DDIM / 64, DICT / 64), 256, 0, stream>>>(W_enc, wth, wtl);
    k_gemm_mfma<<<dim3(DICT / 128, BATCH / 128), 256, 0, stream>>>(
        ahp, alp, wth, wtl, b_enc, acts);
  } else {
    k_gemm_f32<<<dim3(DICT / BN, BATCH / BM), 256, 0, stream>>>(x_enc, W_enc, b_enc, acts);
  }
  k_histA<<<2048, 256, 0, stream>>>((const float4*)acts, wsu + WS_HISTA);
  k_sel<4096><<<1, 256, 0, stream>>>(wsu + WS_HISTA, ctrl, 0);
  k_histB<<<2048, 256, 0, stream>>>((const float4*)acts, ctrl, wsu + WS_HISTB);
  k_sel<4096><<<1, 256, 0, stream>>>(wsu + WS_HISTB, ctrl, 1);
  k_histC<<<2048, 256, 0, stream>>>((const float4*)acts, ctrl, wsu + WS_HISTC);
  k_sel<256><<<1, 256, 0, stream>>>(wsu + WS_HISTC, ctrl, 2);
  k_fused<<<2048, 256, 0, stream>>>((const float4*)acts, ctrl, wsu + WS_COLCNT, wsu + WS_CANDS);
  k_refine_v<<<CAND_CAP, 256, 0, stream>>>(x_in, W_enc, b_enc, b_dec, ctrl,
                                           wsu + WS_CANDS, rmean_d, rinv_d, v64);
  k_refine_apply<<<1, 256, 0, stream>>>(acts, ctrl, wsu + WS_COLCNT, wsu + WS_CANDS, v64,
                                        wsu + WS_PROMO);
  k_dead<<<DICT / 256, 256, 0, stream>>>(nba, wsu + WS_COLCNT, scal, wsu + WS_CANDS,
                                         out + OFF_NBA);
  k_aux<<<dim3(DDIM / 256, BATCH), 256, 0, stream>>>(acts, W_dec, scal, wsu + WS_CANDS, y_aux);
  k_row<<<BATCH, 256, 0, stream>>>(acts, W_dec, b_dec, y_proc, y_mean, y_std, y_aux,
                                   ctrl, wsu + WS_PROMO, scal, out + OFF_YPRED);
  k_fin<<<1, 64, 0, stream>>>(scal, out + OFF_SCAL);
}